// Round 5
// baseline (695.502 us; speedup 1.0000x reference)
//
#include <hip/hip_runtime.h>
#include <math.h>

// dims
#define RN   16      // rims
#define CN   64      // channels
#define HDN  4       // heads
#define DN   16      // depth
#define KN   4       // top-k
#define HWN  4096    // 64*64 pixels per image
#define NPIX 32768   // B*H*W
#define OCN  1024    // R*HD*D
#define CHW  (CN*HWN)
#define PT   32      // pixels per tile -> 1024 blocks -> 4 blocks/CU
#define NE   (PT*KN) // binned entries per block = 128

// One block = 32 pixels. 256 threads (4 waves), 1024 blocks -> 4 blocks/CU
// (16 waves/CU). __launch_bounds__(256,4): 2nd arg is min-BLOCKS/CU on this
// toolchain -> VGPR cap 128.
// P1 head-pair combine is BIT-EXACT vs round-0: hp=0 lane computes s0+s1
// sequentially; hp=1 lane keeps s2,s3 separate; two shfl_xor(32) deliver
// them and the total is ((s0+s1)+s2)+s3 — same association as the passing
// kernel, so top-k selections reproduce exactly (a reorder here flipped
// selections and failed round 4).
__global__ __launch_bounds__(256, 4) void rims_fused(
    const float* __restrict__ x,   const float* __restrict__ rims,
    const float* __restrict__ Wk,  const float* __restrict__ bk,
    const float* __restrict__ Wv,  const float* __restrict__ bv,
    const float* __restrict__ Wq,  const float* __restrict__ bq,
    const float* __restrict__ Wm,  const float* __restrict__ bm,
    const float* __restrict__ Wo,  const float* __restrict__ bo,
    float* __restrict__ out)
{
  __shared__ float q_s[OCN];         // 4 KB   relu(Wq rims + bq)
  __shared__ float ipn_s[64];        //        null-branch logits per (r,h)
  __shared__ float sc_s[16 * 33];    // 2.1KB  scores [r][pix], pad 33
  __shared__ float macc_s[PT * 65];  // 8.3KB  merged-sum accum [pix][c], pad 65
  __shared__ int   bcnt[16];
  __shared__ int   bpos[16];
  __shared__ unsigned char brim[NE];
  __shared__ unsigned char bpix[NE];

  const int tid   = threadIdx.x;
  const int tile  = blockIdx.x;           // 0..1023
  const int b     = tile >> 7;            // image index (128 tiles/image)
  const int pbase = (tile & 127) * PT;    // pixel offset within image
  const float* xbase = x + (size_t)b * CHW + pbase;

  // ---- P0: q = relu(Wq . rims + bq), per-block recompute (65K MACs, tiny) ----
  for (int o = tid; o < OCN; o += 256) {
    const int r = o >> 6;
    const float* wq = Wq + o * CN;
    const float* rp = rims + r * CN;
    float a0 = bq[o], a1 = 0.f, a2 = 0.f, a3 = 0.f;
    #pragma unroll
    for (int c = 0; c < CN; c += 4) {
      a0 = fmaf(wq[c+0], rp[c+0], a0);
      a1 = fmaf(wq[c+1], rp[c+1], a1);
      a2 = fmaf(wq[c+2], rp[c+2], a2);
      a3 = fmaf(wq[c+3], rp[c+3], a3);
    }
    q_s[o] = fmaxf((a0 + a1) + (a2 + a3), 0.f);
  }
  __syncthreads();
  if (tid < 64) {   // ip_null[rh] = sum_d relu(bk) * q   (zero-input branch)
    float acc = 0.f;
    #pragma unroll
    for (int d = 0; d < DN; ++d)
      acc = fmaf(fmaxf(bk[tid * DN + d], 0.f), q_s[tid * DN + d], acc);
    ipn_s[tid] = acc;
  }
  __syncthreads();

  // ---- P1: scores. wave g: rims 4g..4g+3. lane = pixel (bits 0-4) x
  // head-pair (bit 5). Weight rows wave-uniform -> scalar s_loads. ----
  {
    const int pl = tid & 31;            // pixel in tile
    const int hp = (tid >> 5) & 1;      // head-pair
    const int g  = tid >> 6;            // wave -> rim group
    const float* xp = xbase + pl;
    float xv[CN];
    #pragma unroll
    for (int c = 0; c < CN; ++c) xv[c] = xp[c * HWN];   // coalesced, L1-hot

    #pragma unroll 1
    for (int rr = 0; rr < 4; ++rr) {
      const int r = g * 4 + rr;
      float sa = 0.f, sb = 0.f;   // hp=0: sa=s0+s1; hp=1: sa=s2, sb=s3
      #pragma unroll 1
      for (int hh = 0; hh < 2; ++hh) {
        const int h  = hp * 2 + hh;
        const int rh = r * HDN + h;
        float qrow[DN];
        #pragma unroll
        for (int d = 0; d < DN; ++d) qrow[d] = q_s[rh * DN + d];
        const float ipn = ipn_s[rh];
        float ip = 0.f;
        #pragma unroll 1
        for (int d = 0; d < DN; ++d) {
          const float qv = qrow[d];
          if (qv != 0.f) {      // uniform across wave: real skip (~50% of rows)
            const int o = rh * DN + d;
            const float* w = Wk + o * CN;   // uniform addr -> scalar loads
            float a0 = bk[o], a1 = 0.f, a2 = 0.f, a3 = 0.f;
            #pragma unroll
            for (int c = 0; c < CN; c += 4) {
              a0 = fmaf(w[c+0], xv[c+0], a0);
              a1 = fmaf(w[c+1], xv[c+1], a1);
              a2 = fmaf(w[c+2], xv[c+2], a2);
              a3 = fmaf(w[c+3], xv[c+3], a3);
            }
            ip = fmaf(fmaxf((a0 + a1) + (a2 + a3), 0.f), qv, ip);
          }
        }
        // softmax over {real, null} == sigmoid(ip - ipn)
        const float sig = 1.f / (1.f + expf(ipn - ip));
        if (hh == 0)      sa = sig;          // s0 (hp=0) or s2 (hp=1)
        else if (hp == 0) sa += sig;         // s0+s1, sequential order
        else              sb = sig;          // s3 kept separate
      }
      const float ua = __shfl_xor(sa, 32);   // hp=0 lane receives s2
      const float ub = __shfl_xor(sb, 32);   // hp=0 lane receives s3
      if (hp == 0) sc_s[r * 33 + pl] = (sa + ua) + ub;  // ((s0+s1)+s2)+s3
    }
  }
  __syncthreads();

  // ---- P2: zero accum, top-4 selection, block-local rim binning ----
  for (int i = tid; i < PT * 65; i += 256) macc_s[i] = 0.f;
  if (tid < 16) bcnt[tid] = 0;
  __syncthreads();

  int rs0 = 0, rs1 = 0, rs2 = 0, rs3 = 0;
  if (tid < PT) {
    float s[RN];
    #pragma unroll
    for (int r = 0; r < RN; ++r) s[r] = sc_s[r * 33 + tid];
    // strict > picks first (lowest-index) max: matches jax.lax.top_k tie order
    #pragma unroll
    for (int k = 0; k < KN; ++k) {
      float best = -3.4e38f; int bi = 0;
      #pragma unroll
      for (int r = 0; r < RN; ++r) { if (s[r] > best) { best = s[r]; bi = r; } }
      if (k == 0) rs0 = bi; else if (k == 1) rs1 = bi;
      else if (k == 2) rs2 = bi; else rs3 = bi;
      s[bi] = -3.4e38f;
    }
    atomicAdd(&bcnt[rs0], 1); atomicAdd(&bcnt[rs1], 1);
    atomicAdd(&bcnt[rs2], 1); atomicAdd(&bcnt[rs3], 1);
  }
  __syncthreads();
  if (tid == 0) {
    int run = 0;
    #pragma unroll
    for (int r = 0; r < RN; ++r) { bpos[r] = run; run += bcnt[r]; }
  }
  __syncthreads();
  if (tid < PT) {
    int p0 = atomicAdd(&bpos[rs0], 1); brim[p0] = (unsigned char)rs0; bpix[p0] = (unsigned char)tid;
    int p1 = atomicAdd(&bpos[rs1], 1); brim[p1] = (unsigned char)rs1; bpix[p1] = (unsigned char)tid;
    int p2 = atomicAdd(&bpos[rs2], 1); brim[p2] = (unsigned char)rs2; bpix[p2] = (unsigned char)tid;
    int p3 = atomicAdd(&bpos[rs3], 1); brim[p3] = (unsigned char)rs3; bpix[p3] = (unsigned char)tid;
  }
  __syncthreads();

  // ---- P3: 2 threads per binned (pixel, rim) entry (128 entries), split by
  // output-channel half. xv[32] + macc[32] per thread; val partials combined
  // via shfl_xor(1) (partner = adjacent lane). Entries sorted by rim ->
  // mostly rim-uniform waves -> weight gathers hit 1-3 cache lines. ----
  {
    const int e   = tid >> 1;              // entry 0..127
    const int ch  = tid & 1;               // c-half: 0 -> c 0..31, 1 -> 32..63
    const int rim = (int)brim[e];
    const int pp  = (int)bpix[e];
    const int cbeg = ch * 32;
    const float* xp = xbase + pp;
    float xv[32];
    #pragma unroll
    for (int c = 0; c < 32; ++c) xv[c] = xp[(cbeg + c) * HWN];

    float macc[32];
    const float* bmp = bm + rim * CN + cbeg;
    #pragma unroll
    for (int c = 0; c < 32; ++c) macc[c] = bmp[c];   // disjoint c -> bias once

    const float* wvb = Wv + (size_t)(rim * 64) * CN + cbeg;
    const float* bvp = bv + rim * 64;
    const float* wmb = Wm + (size_t)(rim * CN) * 64;

    #pragma unroll 1
    for (int d0 = 0; d0 < 64; d0 += 8) {   // 8 val channels per pass
      float vald[8];
      #pragma unroll
      for (int k8 = 0; k8 < 8; ++k8) {
        const int d = d0 + k8;
        const float* w = wvb + d * CN;     // this thread's 32-channel slice
        float a0 = ch ? 0.f : bvp[d];      // bias added by half 0 only
        float a1 = 0.f, a2 = 0.f, a3 = 0.f;
        #pragma unroll
        for (int c = 0; c < 32; c += 4) {
          a0 = fmaf(w[c+0], xv[c+0], a0);
          a1 = fmaf(w[c+1], xv[c+1], a1);
          a2 = fmaf(w[c+2], xv[c+2], a2);
          a3 = fmaf(w[c+3], xv[c+3], a3);
        }
        float part = (a0 + a1) + (a2 + a3);
        part += __shfl_xor(part, 1);       // combine c-halves (same entry)
        vald[k8] = fmaxf(part, 0.f);
      }
      #pragma unroll
      for (int c = 0; c < 32; ++c) {
        const float* wm = wmb + (cbeg + c) * 64 + d0;   // row-contiguous Wm
        float m = macc[c];
        #pragma unroll
        for (int k8 = 0; k8 < 8; ++k8) m = fmaf(wm[k8], vald[k8], m);
        macc[c] = m;
      }
    }
    #pragma unroll
    for (int c = 0; c < 32; ++c)
      atomicAdd(&macc_s[pp * 65 + cbeg + c], macc[c]);  // pair: 2-way alias,
  }                                                     // free per m136
  __syncthreads();

  // ---- P4: u = relu(mean), out = relu(Wo u + bo). 8 groups x 8 channels,
  // lane pattern: pl = tid&31 (pixel), grp = tid>>5. ----
  {
    const int grp = tid >> 5;              // 0..7
    const int pl  = tid & 31;
    float u[CN];
    #pragma unroll
    for (int c = 0; c < CN; ++c)
      u[c] = fmaxf(macc_s[pl * 65 + c] * 0.25f, 0.f);
    float* op = out + (size_t)b * CHW + pbase + pl;
    #pragma unroll 1
    for (int t = 0; t < 8; ++t) {
      const int co = grp * 8 + t;
      const float* w = Wo + co * CN;       // 2 distinct rows per wave
      float a0 = bo[co], a1 = 0.f, a2 = 0.f, a3 = 0.f;
      #pragma unroll
      for (int c = 0; c < CN; c += 4) {
        a0 = fmaf(w[c+0], u[c+0], a0);
        a1 = fmaf(w[c+1], u[c+1], a1);
        a2 = fmaf(w[c+2], u[c+2], a2);
        a3 = fmaf(w[c+3], u[c+3], a3);
      }
      op[co * HWN] = fmaxf((a0 + a1) + (a2 + a3), 0.f);   // coalesced store
    }
  }
}

extern "C" void kernel_launch(void* const* d_in, const int* in_sizes, int n_in,
                              void* d_out, int out_size, void* d_ws, size_t ws_size,
                              hipStream_t stream) {
  (void)in_sizes; (void)n_in; (void)d_ws; (void)ws_size; (void)out_size;
  const float* xx   = (const float*)d_in[0];
  const float* rims = (const float*)d_in[1];
  const float* Wk   = (const float*)d_in[2];
  const float* bk   = (const float*)d_in[3];
  const float* Wv   = (const float*)d_in[4];
  const float* bv   = (const float*)d_in[5];
  const float* Wq   = (const float*)d_in[6];
  const float* bq   = (const float*)d_in[7];
  const float* Wm   = (const float*)d_in[8];
  const float* bm   = (const float*)d_in[9];
  const float* Wo   = (const float*)d_in[10];
  const float* bo   = (const float*)d_in[11];
  float* outp = (float*)d_out;

  rims_fused<<<dim3(NPIX / PT), dim3(256), 0, stream>>>(
      xx, rims, Wk, bk, Wv, bv, Wq, bq, Wm, bm, Wo, bo, outp);
}

// Round 6
// 611.088 us; speedup vs baseline: 1.1381x; 1.1381x over previous
//
#include <hip/hip_runtime.h>
#include <math.h>

// dims
#define RN   16      // rims
#define CN   64      // channels
#define HDN  4       // heads
#define DN   16      // depth
#define KN   4       // top-k
#define HWN  4096    // 64*64 pixels per image
#define NPIX 32768   // B*H*W
#define OCN  1024    // R*HD*D
#define CHW  (CN*HWN)
#define PT   32      // pixels per tile -> 1024 blocks -> 4 blocks/CU
#define NE   (PT*KN) // binned entries per block = 128

// One block = 32 pixels. 256 threads (4 waves), 1024 blocks -> 4 blocks/CU.
// Empirical __launch_bounds__ VGPR-cap model on this toolchain (4 data
// points): cap = 256/arg regardless of block size. (256,4) capped at 64 and
// spilled (round 5: FETCH 255MB, 1.17TB/s scratch). (256,2) -> cap 128; the
// kernel needs ~100 regs -> fits, and the HW scheduler (not the hint)
// determines residency: 4-wave blocks at <=128 VGPR + 15.4KB LDS = 4
// blocks/CU from the 1024-block grid.
// P1 head-pair combine is BIT-EXACT vs round-0: ((s0+s1)+s2)+s3 association
// preserved via two shfl_xor(32) moves (reorder flips top-k; failed round 4).
__global__ __launch_bounds__(256, 2) void rims_fused(
    const float* __restrict__ x,   const float* __restrict__ rims,
    const float* __restrict__ Wk,  const float* __restrict__ bk,
    const float* __restrict__ Wv,  const float* __restrict__ bv,
    const float* __restrict__ Wq,  const float* __restrict__ bq,
    const float* __restrict__ Wm,  const float* __restrict__ bm,
    const float* __restrict__ Wo,  const float* __restrict__ bo,
    float* __restrict__ out)
{
  __shared__ float q_s[OCN];         // 4 KB   relu(Wq rims + bq)
  __shared__ float ipn_s[64];        //        null-branch logits per (r,h)
  __shared__ float sc_s[16 * 33];    // 2.1KB  scores [r][pix], pad 33
  __shared__ float macc_s[PT * 65];  // 8.3KB  merged-sum accum [pix][c], pad 65
  __shared__ int   bcnt[16];
  __shared__ int   bpos[16];
  __shared__ unsigned char brim[NE];
  __shared__ unsigned char bpix[NE];

  const int tid   = threadIdx.x;
  const int tile  = blockIdx.x;           // 0..1023
  const int b     = tile >> 7;            // image index (128 tiles/image)
  const int pbase = (tile & 127) * PT;    // pixel offset within image
  const float* xbase = x + (size_t)b * CHW + pbase;

  // ---- P0: q = relu(Wq . rims + bq), per-block recompute (65K MACs, tiny) ----
  for (int o = tid; o < OCN; o += 256) {
    const int r = o >> 6;
    const float* wq = Wq + o * CN;
    const float* rp = rims + r * CN;
    float a0 = bq[o], a1 = 0.f, a2 = 0.f, a3 = 0.f;
    #pragma unroll
    for (int c = 0; c < CN; c += 4) {
      a0 = fmaf(wq[c+0], rp[c+0], a0);
      a1 = fmaf(wq[c+1], rp[c+1], a1);
      a2 = fmaf(wq[c+2], rp[c+2], a2);
      a3 = fmaf(wq[c+3], rp[c+3], a3);
    }
    q_s[o] = fmaxf((a0 + a1) + (a2 + a3), 0.f);
  }
  __syncthreads();
  if (tid < 64) {   // ip_null[rh] = sum_d relu(bk) * q   (zero-input branch)
    float acc = 0.f;
    #pragma unroll
    for (int d = 0; d < DN; ++d)
      acc = fmaf(fmaxf(bk[tid * DN + d], 0.f), q_s[tid * DN + d], acc);
    ipn_s[tid] = acc;
  }
  __syncthreads();

  // ---- P1: scores. wave g: rims 4g..4g+3. lane = pixel (bits 0-4) x
  // head-pair (bit 5). Weight rows wave-uniform -> scalar s_loads. ----
  {
    const int pl = tid & 31;            // pixel in tile
    const int hp = (tid >> 5) & 1;      // head-pair
    const int g  = tid >> 6;            // wave -> rim group
    const float* xp = xbase + pl;
    float xv[CN];
    #pragma unroll
    for (int c = 0; c < CN; ++c) xv[c] = xp[c * HWN];   // coalesced, L1-hot

    #pragma unroll 1
    for (int rr = 0; rr < 4; ++rr) {
      const int r = g * 4 + rr;
      float sa = 0.f, sb = 0.f;   // hp=0: sa=s0+s1; hp=1: sa=s2, sb=s3
      #pragma unroll 1
      for (int hh = 0; hh < 2; ++hh) {
        const int h  = hp * 2 + hh;
        const int rh = r * HDN + h;
        float qrow[DN];
        #pragma unroll
        for (int d = 0; d < DN; ++d) qrow[d] = q_s[rh * DN + d];
        const float ipn = ipn_s[rh];
        float ip = 0.f;
        #pragma unroll 1
        for (int d = 0; d < DN; ++d) {
          const float qv = qrow[d];
          if (qv != 0.f) {      // uniform across wave: real skip (~50% of rows)
            const int o = rh * DN + d;
            const float* w = Wk + o * CN;   // uniform addr -> scalar loads
            float a0 = bk[o], a1 = 0.f, a2 = 0.f, a3 = 0.f;
            #pragma unroll
            for (int c = 0; c < CN; c += 4) {
              a0 = fmaf(w[c+0], xv[c+0], a0);
              a1 = fmaf(w[c+1], xv[c+1], a1);
              a2 = fmaf(w[c+2], xv[c+2], a2);
              a3 = fmaf(w[c+3], xv[c+3], a3);
            }
            ip = fmaf(fmaxf((a0 + a1) + (a2 + a3), 0.f), qv, ip);
          }
        }
        // softmax over {real, null} == sigmoid(ip - ipn)
        const float sig = 1.f / (1.f + expf(ipn - ip));
        if (hh == 0)      sa = sig;          // s0 (hp=0) or s2 (hp=1)
        else if (hp == 0) sa += sig;         // s0+s1, sequential order
        else              sb = sig;          // s3 kept separate
      }
      const float ua = __shfl_xor(sa, 32);   // hp=0 lane receives s2
      const float ub = __shfl_xor(sb, 32);   // hp=0 lane receives s3
      if (hp == 0) sc_s[r * 33 + pl] = (sa + ua) + ub;  // ((s0+s1)+s2)+s3
    }
  }
  __syncthreads();

  // ---- P2: zero accum, top-4 selection, block-local rim binning ----
  for (int i = tid; i < PT * 65; i += 256) macc_s[i] = 0.f;
  if (tid < 16) bcnt[tid] = 0;
  __syncthreads();

  int rs0 = 0, rs1 = 0, rs2 = 0, rs3 = 0;
  if (tid < PT) {
    float s[RN];
    #pragma unroll
    for (int r = 0; r < RN; ++r) s[r] = sc_s[r * 33 + tid];
    // strict > picks first (lowest-index) max: matches jax.lax.top_k tie order
    #pragma unroll
    for (int k = 0; k < KN; ++k) {
      float best = -3.4e38f; int bi = 0;
      #pragma unroll
      for (int r = 0; r < RN; ++r) { if (s[r] > best) { best = s[r]; bi = r; } }
      if (k == 0) rs0 = bi; else if (k == 1) rs1 = bi;
      else if (k == 2) rs2 = bi; else rs3 = bi;
      s[bi] = -3.4e38f;
    }
    atomicAdd(&bcnt[rs0], 1); atomicAdd(&bcnt[rs1], 1);
    atomicAdd(&bcnt[rs2], 1); atomicAdd(&bcnt[rs3], 1);
  }
  __syncthreads();
  if (tid == 0) {
    int run = 0;
    #pragma unroll
    for (int r = 0; r < RN; ++r) { bpos[r] = run; run += bcnt[r]; }
  }
  __syncthreads();
  if (tid < PT) {
    int p0 = atomicAdd(&bpos[rs0], 1); brim[p0] = (unsigned char)rs0; bpix[p0] = (unsigned char)tid;
    int p1 = atomicAdd(&bpos[rs1], 1); brim[p1] = (unsigned char)rs1; bpix[p1] = (unsigned char)tid;
    int p2 = atomicAdd(&bpos[rs2], 1); brim[p2] = (unsigned char)rs2; bpix[p2] = (unsigned char)tid;
    int p3 = atomicAdd(&bpos[rs3], 1); brim[p3] = (unsigned char)rs3; bpix[p3] = (unsigned char)tid;
  }
  __syncthreads();

  // ---- P3: 2 threads per binned (pixel, rim) entry (128 entries), split by
  // output-channel half. xv[32] + macc[32] per thread; val partials combined
  // via shfl_xor(1) (partner = adjacent lane). Entries sorted by rim ->
  // mostly rim-uniform waves -> weight gathers hit 1-3 cache lines. ----
  {
    const int e   = tid >> 1;              // entry 0..127
    const int ch  = tid & 1;               // c-half: 0 -> c 0..31, 1 -> 32..63
    const int rim = (int)brim[e];
    const int pp  = (int)bpix[e];
    const int cbeg = ch * 32;
    const float* xp = xbase + pp;
    float xv[32];
    #pragma unroll
    for (int c = 0; c < 32; ++c) xv[c] = xp[(cbeg + c) * HWN];

    float macc[32];
    const float* bmp = bm + rim * CN + cbeg;
    #pragma unroll
    for (int c = 0; c < 32; ++c) macc[c] = bmp[c];   // disjoint c -> bias once

    const float* wvb = Wv + (size_t)(rim * 64) * CN + cbeg;
    const float* bvp = bv + rim * 64;
    const float* wmb = Wm + (size_t)(rim * CN) * 64;

    #pragma unroll 1
    for (int d0 = 0; d0 < 64; d0 += 8) {   // 8 val channels per pass
      float vald[8];
      #pragma unroll
      for (int k8 = 0; k8 < 8; ++k8) {
        const int d = d0 + k8;
        const float* w = wvb + d * CN;     // this thread's 32-channel slice
        float a0 = ch ? 0.f : bvp[d];      // bias added by half 0 only
        float a1 = 0.f, a2 = 0.f, a3 = 0.f;
        #pragma unroll
        for (int c = 0; c < 32; c += 4) {
          a0 = fmaf(w[c+0], xv[c+0], a0);
          a1 = fmaf(w[c+1], xv[c+1], a1);
          a2 = fmaf(w[c+2], xv[c+2], a2);
          a3 = fmaf(w[c+3], xv[c+3], a3);
        }
        float part = (a0 + a1) + (a2 + a3);
        part += __shfl_xor(part, 1);       // combine c-halves (same entry)
        vald[k8] = fmaxf(part, 0.f);
      }
      #pragma unroll
      for (int c = 0; c < 32; ++c) {
        const float* wm = wmb + (cbeg + c) * 64 + d0;   // row-contiguous Wm
        float m = macc[c];
        #pragma unroll
        for (int k8 = 0; k8 < 8; ++k8) m = fmaf(wm[k8], vald[k8], m);
        macc[c] = m;
      }
    }
    #pragma unroll
    for (int c = 0; c < 32; ++c)
      atomicAdd(&macc_s[pp * 65 + cbeg + c], macc[c]);  // pair: 2-way alias,
  }                                                     // free per m136
  __syncthreads();

  // ---- P4: u = relu(mean), out = relu(Wo u + bo). 8 groups x 8 channels,
  // lane pattern: pl = tid&31 (pixel), grp = tid>>5. ----
  {
    const int grp = tid >> 5;              // 0..7
    const int pl  = tid & 31;
    float u[CN];
    #pragma unroll
    for (int c = 0; c < CN; ++c)
      u[c] = fmaxf(macc_s[pl * 65 + c] * 0.25f, 0.f);
    float* op = out + (size_t)b * CHW + pbase + pl;
    #pragma unroll 1
    for (int t = 0; t < 8; ++t) {
      const int co = grp * 8 + t;
      const float* w = Wo + co * CN;       // 2 distinct rows per wave
      float a0 = bo[co], a1 = 0.f, a2 = 0.f, a3 = 0.f;
      #pragma unroll
      for (int c = 0; c < CN; c += 4) {
        a0 = fmaf(w[c+0], u[c+0], a0);
        a1 = fmaf(w[c+1], u[c+1], a1);
        a2 = fmaf(w[c+2], u[c+2], a2);
        a3 = fmaf(w[c+3], u[c+3], a3);
      }
      op[co * HWN] = fmaxf((a0 + a1) + (a2 + a3), 0.f);   // coalesced store
    }
  }
}

extern "C" void kernel_launch(void* const* d_in, const int* in_sizes, int n_in,
                              void* d_out, int out_size, void* d_ws, size_t ws_size,
                              hipStream_t stream) {
  (void)in_sizes; (void)n_in; (void)d_ws; (void)ws_size; (void)out_size;
  const float* xx   = (const float*)d_in[0];
  const float* rims = (const float*)d_in[1];
  const float* Wk   = (const float*)d_in[2];
  const float* bk   = (const float*)d_in[3];
  const float* Wv   = (const float*)d_in[4];
  const float* bv   = (const float*)d_in[5];
  const float* Wq   = (const float*)d_in[6];
  const float* bq   = (const float*)d_in[7];
  const float* Wm   = (const float*)d_in[8];
  const float* bm   = (const float*)d_in[9];
  const float* Wo   = (const float*)d_in[10];
  const float* bo   = (const float*)d_in[11];
  float* outp = (float*)d_out;

  rims_fused<<<dim3(NPIX / PT), dim3(256), 0, stream>>>(
      xx, rims, Wk, bk, Wv, bv, Wq, bq, Wm, bm, Wo, bo, outp);
}

// Round 7
// 540.337 us; speedup vs baseline: 1.2872x; 1.1309x over previous
//
#include <hip/hip_runtime.h>
#include <math.h>

// dims
#define RN   16      // rims
#define CN   64      // channels
#define HDN  4       // heads
#define DN   16      // depth
#define KN   4       // top-k
#define HWN  4096    // 64*64 pixels per image
#define NPIX 32768   // B*H*W
#define OCN  1024    // R*HD*D
#define CHW  (CN*HWN)
#define PT   32      // K2 pixels per tile -> 1024 blocks
#define NE   (PT*KN) // binned entries per K2 block = 128

// ============================ K1: scores ====================================
// grid 2048 = 512 pixel-tiles x 4 rim-groups. 256 threads (4 waves).
// wave g handles ONE rim (rbase+g) for all 64 pixels: weight row address and
// the qv!=0 skip are wave-uniform (scalar s_loads, the round-0 known-good
// path). Per-score arithmetic is bit-identical to the round-0 kernel:
// q dot (4-acc, c+=4), ipn sequential d, ip sequential active-d, score
// accumulated h=0..3 sequentially. Scores -> workspace [R][NPIX], coalesced.
__global__ __launch_bounds__(256, 2) void rims_scores(
    const float* __restrict__ x,   const float* __restrict__ rims,
    const float* __restrict__ Wk,  const float* __restrict__ bk,
    const float* __restrict__ Wq,  const float* __restrict__ bq,
    float* __restrict__ sc)
{
  __shared__ float q_s[256];    // 4 rims x 64 rows
  __shared__ float ipn_s[16];   // 4 rims x 4 heads

  const int tid   = threadIdx.x;
  const int bid   = blockIdx.x;          // 0..2047
  const int tile  = bid >> 2;            // 0..511
  const int rg    = bid & 3;             // rim group
  const int b     = tile >> 6;           // image index
  const int pbase = (tile & 63) * 64;    // pixel offset within image
  const int rbase = rg * 4;              // first rim of this block
  const float* xbase = x + (size_t)b * CHW + pbase;

  // ---- P0: q rows for this block's 4 rims (one row per thread) ----
  {
    const int o = rbase * 64 + tid;      // global row, tid = local row 0..255
    const int r = o >> 6;
    const float* wq = Wq + o * CN;
    const float* rp = rims + r * CN;
    float a0 = bq[o], a1 = 0.f, a2 = 0.f, a3 = 0.f;
    #pragma unroll
    for (int c = 0; c < CN; c += 4) {
      a0 = fmaf(wq[c+0], rp[c+0], a0);
      a1 = fmaf(wq[c+1], rp[c+1], a1);
      a2 = fmaf(wq[c+2], rp[c+2], a2);
      a3 = fmaf(wq[c+3], rp[c+3], a3);
    }
    q_s[tid] = fmaxf((a0 + a1) + (a2 + a3), 0.f);
  }
  __syncthreads();
  if (tid < 16) {   // ip_null for local rh 0..15 (sequential d, as round 0)
    const int rh = rbase * HDN + tid;    // global rh
    float acc = 0.f;
    #pragma unroll
    for (int d = 0; d < DN; ++d)
      acc = fmaf(fmaxf(bk[rh * DN + d], 0.f), q_s[tid * DN + d], acc);
    ipn_s[tid] = acc;
  }
  __syncthreads();

  // ---- P1: wave g -> rim rbase+g, lane = pixel ----
  {
    const int pl = tid & 63;
    const int g  = tid >> 6;
    const int r  = rbase + g;
    const float* xp = xbase + pl;
    float xv[CN];
    #pragma unroll
    for (int c = 0; c < CN; ++c) xv[c] = xp[c * HWN];   // coalesced, L1-hot

    float score = 0.f;
    #pragma unroll 1
    for (int h = 0; h < HDN; ++h) {
      const int rhl = g * HDN + h;       // local rh
      float qrow[DN];
      #pragma unroll
      for (int d = 0; d < DN; ++d) qrow[d] = q_s[rhl * DN + d];
      const float ipn = ipn_s[rhl];
      float ip = 0.f;
      #pragma unroll 1
      for (int d = 0; d < DN; ++d) {
        const float qv = qrow[d];
        if (qv != 0.f) {    // uniform across wave: real skip (~50% of rows)
          const int o = r * 64 + h * DN + d;
          const float* w = Wk + o * CN;  // uniform addr -> scalar loads
          float a0 = bk[o], a1 = 0.f, a2 = 0.f, a3 = 0.f;
          #pragma unroll
          for (int c = 0; c < CN; c += 4) {
            a0 = fmaf(w[c+0], xv[c+0], a0);
            a1 = fmaf(w[c+1], xv[c+1], a1);
            a2 = fmaf(w[c+2], xv[c+2], a2);
            a3 = fmaf(w[c+3], xv[c+3], a3);
          }
          ip = fmaf(fmaxf((a0 + a1) + (a2 + a3), 0.f), qv, ip);
        }
      }
      // softmax over {real, null} == sigmoid(ip - ipn)
      score += 1.f / (1.f + expf(ipn - ip));
    }
    sc[(size_t)r * NPIX + (size_t)b * HWN + pbase + pl] = score;   // coalesced
  }
}

// ====================== K2: top-k + merge + out =============================
// grid 1024 (32-pixel tiles), 256 threads. Round-6's verified P2/P3/P4
// (passed, absmax 1.22e-4), reading exact scores from workspace -> top-k
// selections are bit-identical to the fused round-0 kernel.
__global__ __launch_bounds__(256, 2) void rims_merge(
    const float* __restrict__ x,
    const float* __restrict__ Wv,  const float* __restrict__ bv,
    const float* __restrict__ Wm,  const float* __restrict__ bm,
    const float* __restrict__ Wo,  const float* __restrict__ bo,
    const float* __restrict__ sc,
    float* __restrict__ out)
{
  __shared__ float macc_s[PT * 65];  // 8.3KB merged-sum accum [pix][c], pad 65
  __shared__ int   bcnt[16];
  __shared__ int   bpos[16];
  __shared__ unsigned char brim[NE];
  __shared__ unsigned char bpix[NE];

  const int tid   = threadIdx.x;
  const int tile  = blockIdx.x;           // 0..1023
  const int b     = tile >> 7;            // image index (128 tiles/image)
  const int pbase = (tile & 127) * PT;    // pixel offset within image
  const float* xbase = x + (size_t)b * CHW + pbase;

  // ---- P2: zero accum, top-4 selection from exact scores, rim binning ----
  for (int i = tid; i < PT * 65; i += 256) macc_s[i] = 0.f;
  if (tid < 16) bcnt[tid] = 0;
  __syncthreads();

  int rs0 = 0, rs1 = 0, rs2 = 0, rs3 = 0;
  if (tid < PT) {
    const size_t gp = (size_t)b * HWN + pbase + tid;
    float s[RN];
    #pragma unroll
    for (int r = 0; r < RN; ++r) s[r] = sc[(size_t)r * NPIX + gp];
    // strict > picks first (lowest-index) max: matches jax.lax.top_k tie order
    #pragma unroll
    for (int k = 0; k < KN; ++k) {
      float best = -3.4e38f; int bi = 0;
      #pragma unroll
      for (int r = 0; r < RN; ++r) { if (s[r] > best) { best = s[r]; bi = r; } }
      if (k == 0) rs0 = bi; else if (k == 1) rs1 = bi;
      else if (k == 2) rs2 = bi; else rs3 = bi;
      s[bi] = -3.4e38f;
    }
    atomicAdd(&bcnt[rs0], 1); atomicAdd(&bcnt[rs1], 1);
    atomicAdd(&bcnt[rs2], 1); atomicAdd(&bcnt[rs3], 1);
  }
  __syncthreads();
  if (tid == 0) {
    int run = 0;
    #pragma unroll
    for (int r = 0; r < RN; ++r) { bpos[r] = run; run += bcnt[r]; }
  }
  __syncthreads();
  if (tid < PT) {
    int p0 = atomicAdd(&bpos[rs0], 1); brim[p0] = (unsigned char)rs0; bpix[p0] = (unsigned char)tid;
    int p1 = atomicAdd(&bpos[rs1], 1); brim[p1] = (unsigned char)rs1; bpix[p1] = (unsigned char)tid;
    int p2 = atomicAdd(&bpos[rs2], 1); brim[p2] = (unsigned char)rs2; bpix[p2] = (unsigned char)tid;
    int p3 = atomicAdd(&bpos[rs3], 1); brim[p3] = (unsigned char)rs3; bpix[p3] = (unsigned char)tid;
  }
  __syncthreads();

  // ---- P3: 2 threads per binned (pixel, rim) entry (128 entries), split by
  // output-channel half. xv[32] + macc[32] per thread; val partials combined
  // via shfl_xor(1) (partner = adjacent lane). Entries sorted by rim ->
  // mostly rim-uniform waves -> weight gathers hit 1-3 cache lines. ----
  {
    const int e   = tid >> 1;              // entry 0..127
    const int ch  = tid & 1;               // c-half: 0 -> c 0..31, 1 -> 32..63
    const int rim = (int)brim[e];
    const int pp  = (int)bpix[e];
    const int cbeg = ch * 32;
    const float* xp = xbase + pp;
    float xv[32];
    #pragma unroll
    for (int c = 0; c < 32; ++c) xv[c] = xp[(cbeg + c) * HWN];

    float macc[32];
    const float* bmp = bm + rim * CN + cbeg;
    #pragma unroll
    for (int c = 0; c < 32; ++c) macc[c] = bmp[c];   // disjoint c -> bias once

    const float* wvb = Wv + (size_t)(rim * 64) * CN + cbeg;
    const float* bvp = bv + rim * 64;
    const float* wmb = Wm + (size_t)(rim * CN) * 64;

    #pragma unroll 1
    for (int d0 = 0; d0 < 64; d0 += 8) {   // 8 val channels per pass
      float vald[8];
      #pragma unroll
      for (int k8 = 0; k8 < 8; ++k8) {
        const int d = d0 + k8;
        const float* w = wvb + d * CN;     // this thread's 32-channel slice
        float a0 = ch ? 0.f : bvp[d];      // bias added by half 0 only
        float a1 = 0.f, a2 = 0.f, a3 = 0.f;
        #pragma unroll
        for (int c = 0; c < 32; c += 4) {
          a0 = fmaf(w[c+0], xv[c+0], a0);
          a1 = fmaf(w[c+1], xv[c+1], a1);
          a2 = fmaf(w[c+2], xv[c+2], a2);
          a3 = fmaf(w[c+3], xv[c+3], a3);
        }
        float part = (a0 + a1) + (a2 + a3);
        part += __shfl_xor(part, 1);       // combine c-halves (same entry)
        vald[k8] = fmaxf(part, 0.f);
      }
      #pragma unroll
      for (int c = 0; c < 32; ++c) {
        const float* wm = wmb + (cbeg + c) * 64 + d0;   // row-contiguous Wm
        float m = macc[c];
        #pragma unroll
        for (int k8 = 0; k8 < 8; ++k8) m = fmaf(wm[k8], vald[k8], m);
        macc[c] = m;
      }
    }
    #pragma unroll
    for (int c = 0; c < 32; ++c)
      atomicAdd(&macc_s[pp * 65 + cbeg + c], macc[c]);  // pair: 2-way alias,
  }                                                     // free per m136
  __syncthreads();

  // ---- P4: u = relu(mean), out = relu(Wo u + bo). 8 groups x 8 channels ----
  {
    const int grp = tid >> 5;              // 0..7
    const int pl  = tid & 31;
    float u[CN];
    #pragma unroll
    for (int c = 0; c < CN; ++c)
      u[c] = fmaxf(macc_s[pl * 65 + c] * 0.25f, 0.f);
    float* op = out + (size_t)b * CHW + pbase + pl;
    #pragma unroll 1
    for (int t = 0; t < 8; ++t) {
      const int co = grp * 8 + t;
      const float* w = Wo + co * CN;       // 2 distinct rows per wave
      float a0 = bo[co], a1 = 0.f, a2 = 0.f, a3 = 0.f;
      #pragma unroll
      for (int c = 0; c < CN; c += 4) {
        a0 = fmaf(w[c+0], u[c+0], a0);
        a1 = fmaf(w[c+1], u[c+1], a1);
        a2 = fmaf(w[c+2], u[c+2], a2);
        a3 = fmaf(w[c+3], u[c+3], a3);
      }
      op[co * HWN] = fmaxf((a0 + a1) + (a2 + a3), 0.f);   // coalesced store
    }
  }
}

extern "C" void kernel_launch(void* const* d_in, const int* in_sizes, int n_in,
                              void* d_out, int out_size, void* d_ws, size_t ws_size,
                              hipStream_t stream) {
  (void)in_sizes; (void)n_in; (void)ws_size; (void)out_size;
  const float* xx   = (const float*)d_in[0];
  const float* rims = (const float*)d_in[1];
  const float* Wk   = (const float*)d_in[2];
  const float* bk   = (const float*)d_in[3];
  const float* Wv   = (const float*)d_in[4];
  const float* bv   = (const float*)d_in[5];
  const float* Wq   = (const float*)d_in[6];
  const float* bq   = (const float*)d_in[7];
  const float* Wm   = (const float*)d_in[8];
  const float* bm   = (const float*)d_in[9];
  const float* Wo   = (const float*)d_in[10];
  const float* bo   = (const float*)d_in[11];
  float* outp = (float*)d_out;
  float* sc   = (float*)d_ws;   // 16 x 32768 fp32 = 2 MB score buffer

  rims_scores<<<dim3(2048), dim3(256), 0, stream>>>(
      xx, rims, Wk, bk, Wq, bq, sc);
  rims_merge<<<dim3(1024), dim3(256), 0, stream>>>(
      xx, Wv, bv, Wm, bm, Wo, bo, sc, outp);
}